// Round 6
// baseline (238.089 us; speedup 1.0000x reference)
//
#include <hip/hip_runtime.h>
#include <math.h>

// SteeredConvTranspose2d on MI355X — round 6 (round 5 + global_load_lds src fix).
// setup (prep weights*basis -> bf16  +  transpose/pad/pre-swizzle x -> Xt) ;
// fused conv: explicit 2-stage software pipeline (ks0/ks1 register sets),
// X staged via global_load_lds (contiguous, pre-swizzled, PER-LANE global src),
// epilogue in-reg.
//
// ws layout (bytes):
//   [0       .. 802816)    KA bf16 [e 49][uv 2][oc 64][i 64]
//   [802816  .. 1826816)   KB bf16 [e 25][oc 320][i 64]
//   [2097152 .. +4734976)  Xt bf16 [8][68][68][64]  zero-padded halo, granule-swizzled

namespace {

typedef float f4 __attribute__((ext_vector_type(4)));
typedef short s8 __attribute__((ext_vector_type(8)));

constexpr int NKA = 401408;   // 49*2*64*64
constexpr int NKB = 512000;   // 25*320*64

__device__ __forceinline__ unsigned short f2bf(float f) {
    unsigned int u = __float_as_uint(f);
    u += 0x7fffu + ((u >> 16) & 1u);
    return (unsigned short)(u >> 16);
}

template <int PY, int PX>
constexpr unsigned bmaskA() {
    constexpr int NXA = 4 - PX, NYA = 4 - PY, NXB = 2 + PX, NYB = 2 + PY;
    unsigned m = 0;
    for (int t = 0; t < NYA * NXA; ++t) {
        int tyi = t / NXA, txi = t % NXA;
        int ty = tyi - (1 - PY), tx = txi - (1 - PX);
        if (ty >= 0 && ty < NYB && tx >= 0 && tx < NXB) m |= 1u << t;
    }
    return m;
}

// ---------------- setup: prep (weights*basis) + transpose/pad/swizzle x ----------------
__device__ void prep_body(
    const float* __restrict__ w0, const float* __restrict__ wc,
    const float* __restrict__ wsn, const float* __restrict__ wa,
    unsigned short* __restrict__ KA, unsigned short* __restrict__ KB,
    const float* SA, const float* S5)
{
    const int idx = blockIdx.x * 256 + threadIdx.x;
    if (idx < NKA) {
        int i = idx & 63;
        int e = idx >> 6;
        int oc = e & 63; e >>= 6;
        int uv = e & 1;  e >>= 1;     // e in [0,49) cumulative tap over parities {16,12,12,9}
        int par = (e < 16) ? 0 : (e < 28) ? 1 : (e < 40) ? 2 : 3;
        int t = e - ((par == 0) ? 0 : (par == 1) ? 16 : (par == 2) ? 28 : 40);
        int py = par >> 1, px = par & 1;
        int nx = 4 - px;
        int tyi = t / nx, txi = t % nx;
        float dy = (float)(2 * tyi + py - 3), dx = (float)(2 * txi + px - 3);
        float rr = sqrtf(dy * dy + dx * dx);
        float phi = atan2f(dy, dx);
        const float* wr = wa + (oc * 64 + i) * 3;
        float v = 0.f;
#pragma unroll
        for (int r = 0; r < 3; ++r) { float d = rr - (float)(r + 1); v += wr[r] * (expf(-2.f * d * d) / SA[r]); }
        float tr = uv ? sinf(phi) : cosf(phi);
        KA[idx] = f2bf(v * tr);
    } else if (idx < NKA + NKB) {
        int j = idx - NKA;
        int i = j & 63;
        int rest = j >> 6;
        int oc = rest % 320;
        int e = rest / 320;           // [0,25) cumulative tap over parities {4,6,6,9}
        int par = (e < 4) ? 0 : (e < 10) ? 1 : (e < 16) ? 2 : 3;
        int t = e - ((par == 0) ? 0 : (par == 1) ? 4 : (par == 2) ? 10 : 16);
        int py = par >> 1, px = par & 1;
        int nx = 2 + px;
        int tyi = t / nx, txi = t % nx;
        float dy = (float)(2 * tyi - 1 - py), dx = (float)(2 * txi - 1 - px);
        float rr = sqrtf(dy * dy + dx * dx);
        float phi = atan2f(dy, dx);
        int g = oc >> 6, o = oc & 63;
        float v = 0.f;
        if (g == 0) {
            const float* wr = w0 + (o * 64 + i) * 3;
#pragma unroll
            for (int r = 0; r < 3; ++r) { float d = rr - (float)r; v += wr[r] * (expf(-2.f * d * d) / S5[r]); }
        } else {
            int k = (g - 1) >> 1, sn = (g - 1) & 1;
            const float* wsel = ((sn == 0) ? wc : wsn) + ((k * 64 + o) * 64 + i) * 2;
            float s = 0.f;
#pragma unroll
            for (int r = 0; r < 2; ++r) { float d = rr - (float)(r + 1); s += wsel[r] * (expf(-2.f * d * d) / S5[r + 1]); }
            float ang = (float)(k + 1) * phi;
            v = s * ((sn == 0) ? cosf(ang) : sinf(ang));
        }
        KB[j] = f2bf(v);
    }
}

// x fp32 NCHW -> Xt bf16 [b][iyp 68][ixp 68][granule-swizzled ch 64]
// granule slot = (ch>>3) ^ (ixp & 7)  (involution; fused staging is then linear)
__device__ void transpose_body(
    const float* __restrict__ x, unsigned short* __restrict__ Xt, float* LFraw)
{
    float (*LF)[65] = (float (*)[65])LFraw;
    const int t = threadIdx.x;
    const int j = blockIdx.x - 3568;
    const int iyp = j % 68, b = j / 68;
    const int iy = iyp - 2;
    unsigned int* Xtu = (unsigned int*)(Xt + (size_t)(b * 68 + iyp) * 68 * 64);
    if (iy < 0 || iy >= 64) {
        for (int k = t; k < 68 * 32; k += 256) Xtu[k] = 0u;
        return;
    }
    const float* xb = x + (size_t)b * 262144 + iy * 64;
#pragma unroll
    for (int it = 0; it < 16; ++it) {
        int ch = it * 4 + (t >> 6);
        LF[ch][t & 63] = xb[(size_t)ch * 4096 + (t & 63)];
    }
    __syncthreads();
    if (t < 128) {   // zero border cols ixp in {0,1,66,67}
        int colidx = t >> 5;
        int ixp = (colidx < 2) ? colidx : 64 + colidx;
        Xtu[ixp * 32 + (t & 31)] = 0u;
    }
    const int lane = t & 63, w = t >> 6;
#pragma unroll
    for (int k = 0; k < 8; ++k) {
        int it = w * 8 + k;                 // 0..31
        int ix = 2 * it + (lane >> 5);      // 0..63
        int ch = 2 * (lane & 31);
        unsigned int pack = (unsigned int)f2bf(LF[ch][ix]) | ((unsigned int)f2bf(LF[ch + 1][ix]) << 16);
        const int ixp = ix + 2;
        const int gslot = ((lane & 31) >> 2) ^ (ixp & 7);
        Xtu[ixp * 32 + gslot * 4 + ((lane & 31) & 3)] = pack;
    }
}

__global__ __launch_bounds__(256) void setup_kernel(
    const float* __restrict__ w0, const float* __restrict__ wc,
    const float* __restrict__ wsn, const float* __restrict__ wa,
    const float* __restrict__ x,
    unsigned short* __restrict__ KA, unsigned short* __restrict__ KB,
    unsigned short* __restrict__ Xt,
    float sa0, float sa1, float sa2, float s50, float s51, float s52)
{
    __shared__ float LFraw[64 * 65];
    const float SA[3] = {sa0, sa1, sa2};
    const float S5[3] = {s50, s51, s52};
    if (blockIdx.x < 3568) prep_body(w0, wc, wsn, wa, KA, KB, SA, S5);
    else                   transpose_body(x, Xt, LFraw);
}

// ---------------- fused conv: explicitly pipelined MFMA loop ----------------
template <int PY, int PX>
__device__ __forceinline__ void mfma_loop(
    const unsigned short* __restrict__ Xs,
    const unsigned short* __restrict__ KA, const unsigned short* __restrict__ KB,
    const float* __restrict__ bias, float* __restrict__ out,
    int b, int oy, int obase, int lr, int hi)
{
    constexpr int NXA = 4 - PX, NYA = 4 - PY, NTA = NYA * NXA;
    constexpr int PAR = 2 * PY + PX;
    constexpr int TBA = (PAR == 0) ? 0 : (PAR == 1) ? 16 : (PAR == 2) ? 28 : 40;
    constexpr int TBB = (PAR == 0) ? 0 : (PAR == 1) ? 4  : (PAR == 2) ? 10 : 16;
    constexpr unsigned BM = bmaskA<PY, PX>();

    const unsigned short* ka = KA + TBA * 8192  + (obase + lr) * 64 + hi * 8;
    const unsigned short* kb = KB + TBB * 20480 + (obase + lr) * 64 + hi * 8;

    f4 accA[2][4];
    f4 accB[5][4];
#pragma unroll
    for (int uv = 0; uv < 2; ++uv)
#pragma unroll
        for (int ni = 0; ni < 4; ++ni) accA[uv][ni] = f4{0.f, 0.f, 0.f, 0.f};
#pragma unroll
    for (int g = 0; g < 5; ++g)
#pragma unroll
        for (int ni = 0; ni < 4; ++ni) accB[g][ni] = f4{0.f, 0.f, 0.f, 0.f};

    s8 a0[2], a1[2], g0[5], g1[5], x0[4], x1[4];

    auto loadA = [&](s8 (&d)[2], int t, int ks) {
#pragma unroll
        for (int uv = 0; uv < 2; ++uv)
            d[uv] = *(const s8*)(ka + t * 8192 + uv * 4096 + ks * 32);
    };
    auto loadG = [&](s8 (&d)[5], int tB, int ks) {
#pragma unroll
        for (int g = 0; g < 5; ++g)
            d[g] = *(const s8*)(kb + tB * 20480 + g * 4096 + ks * 32);
    };
    auto loadX = [&](s8 (&d)[4], int tyi, int txi, int ks) {
#pragma unroll
        for (int ni = 0; ni < 4; ++ni) {
            const int rx = ni * 16 + lr + txi + PX;
            const int gz = (ks * 4 + hi) ^ (rx & 7);
            d[ni] = *(const s8*)(Xs + ((tyi * 68 + rx) * 8 + gz) * 8);
        }
    };
    auto mmA = [&](s8 (&a)[2], s8 (&xx)[4]) {
#pragma unroll
        for (int uv = 0; uv < 2; ++uv)
#pragma unroll
            for (int ni = 0; ni < 4; ++ni)
                accA[uv][ni] = __builtin_amdgcn_mfma_f32_16x16x32_bf16(a[uv], xx[ni], accA[uv][ni], 0, 0, 0);
    };
    auto mmB = [&](s8 (&gg)[5], s8 (&xx)[4]) {
#pragma unroll
        for (int g = 0; g < 5; ++g)
#pragma unroll
            for (int ni = 0; ni < 4; ++ni)
                accB[g][ni] = __builtin_amdgcn_mfma_f32_16x16x32_bf16(gg[g], xx[ni], accB[g][ni], 0, 0, 0);
    };

    // prologue: ks=0 of tap 0 in flight
    loadA(a0, 0, 0);
    loadX(x0, 0, 0, 0);
    if (BM & 1u) loadG(g0, 0, 0);

    int tyi = 0, txi = 0, tB = 0;
#pragma unroll
    for (int t = 0; t < NTA; ++t) {
        const bool bv = (BM >> t) & 1u;
        // issue ks=1 set
        loadA(a1, t, 1);
        loadX(x1, tyi, txi, 1);
        if (bv) loadG(g1, tB, 1);
        // compute ks=0 set
        mmA(a0, x0);
        if (bv) mmB(g0, x0);
        // issue next-tap ks=0 set
        const int txn = (txi + 1 == NXA) ? 0 : txi + 1;
        const int tyn = (txi + 1 == NXA) ? tyi + 1 : tyi;
        if (t + 1 < NTA) {
            loadA(a0, t + 1, 0);
            loadX(x0, tyn, txn, 0);
            if ((BM >> (t + 1)) & 1u) loadG(g0, tB + (bv ? 1 : 0), 0);
        }
        // compute ks=1 set
        mmA(a1, x1);
        if (bv) { mmB(g1, x1); ++tB; }
        tyi = tyn; txi = txn;
    }

    // epilogue: gating + bias
    const int yy = 2 * oy + PY;
#pragma unroll
    for (int ni = 0; ni < 4; ++ni) {
        const int px = ni * 16 + lr;
        const int xx = 2 * px + PX;
#pragma unroll
        for (int r2 = 0; r2 < 4; ++r2) {
            const int o = obase + hi * 4 + r2;
            const float u = accA[0][ni][r2], v = accA[1][ni][r2];
            const float rho_raw = sqrtf(u * u + v * v + 1e-8f);
            const float un = u / rho_raw, vn = v / rho_raw;
            const float rho = tanhf(rho_raw);
            const float c2 = (un - vn) * (un + vn);
            const float sp = 2.f * un * vn;
            out[((b * 64 + o) * 128 + yy) * 128 + xx] =
                accB[0][ni][r2]
                + rho * (un * accB[1][ni][r2] + vn * accB[2][ni][r2]
                       + c2 * accB[3][ni][r2] + sp * accB[4][ni][r2])
                + bias[o];
        }
    }
}

template <int PY>
__device__ __forceinline__ void fused_body(
    const unsigned short* __restrict__ Xt,
    const unsigned short* __restrict__ KA, const unsigned short* __restrict__ KB,
    const float* __restrict__ bias, float* __restrict__ out,
    int oh, unsigned short* Xs)
{
    constexpr int NYA = 4 - PY;
    const int tid = threadIdx.x;
    const int oy = blockIdx.x, b = blockIdx.y;

    // ---- stage NYA contiguous rows of (pre-swizzled) Xt into LDS via global_load_lds ----
    // LDS dest: wave-uniform base (HW scatters lane*16B). Global src: PER-LANE address.
    {
        const int iy0p = oy + PY;                         // first padded row
        const int lane = tid & 63;
        const unsigned short* src = Xt + ((size_t)b * 68 + iy0p) * 68 * 64;
        constexpr int NCH = (NYA * 68 * 8 + 63) / 64;     // 64-granule (1 KiB) chunks
        const int wv = tid >> 6;
        for (int c = wv; c < NCH; c += 4)
            __builtin_amdgcn_global_load_lds((const unsigned int*)(src + c * 512 + lane * 8),
                                             (unsigned int*)(Xs + c * 512), 16, 0, 0);
    }
    __syncthreads();

    const int lane = tid & 63, lr = lane & 15, hi = lane >> 4;
    const int w = tid >> 6;
    const int p = w & 1, mq = w >> 1;
    const int obase = oh * 32 + mq * 16;

    if (p == 0)
        mfma_loop<PY, 0>(Xs, KA, KB, bias, out, b, oy, obase, lr, hi);
    else
        mfma_loop<PY, 1>(Xs, KA, KB, bias, out, b, oy, obase, lr, hi);
}

__global__ __launch_bounds__(256, 2) void fused_kernel(
    const unsigned short* __restrict__ Xt,
    const unsigned short* __restrict__ KA, const unsigned short* __restrict__ KB,
    const float* __restrict__ bias, float* __restrict__ out)
{
    __shared__ __align__(16) unsigned short Xs[4 * 68 * 64];
    const int z = blockIdx.z;
    const int oh = z >> 1;
    if (z & 1) fused_body<1>(Xt, KA, KB, bias, out, oh, Xs);
    else       fused_body<0>(Xt, KA, KB, bias, out, oh, Xs);
}

} // namespace

extern "C" void kernel_launch(void* const* d_in, const int* in_sizes, int n_in,
                              void* d_out, int out_size, void* d_ws, size_t ws_size,
                              hipStream_t stream)
{
    const float* x    = (const float*)d_in[0];
    const float* w0   = (const float*)d_in[1];
    const float* wc   = (const float*)d_in[2];
    const float* wsn  = (const float*)d_in[3];
    const float* wa   = (const float*)d_in[4];
    const float* bias = (const float*)d_in[5];
    float* out = (float*)d_out;

    char* wsb = (char*)d_ws;
    unsigned short* KA = (unsigned short*)(wsb);
    unsigned short* KB = (unsigned short*)(wsb + 802816);
    unsigned short* Xt = (unsigned short*)(wsb + 2097152);

    // host-side radial normalization constants (pure CPU math, capture-safe)
    float SA[3] = {0.f, 0.f, 0.f}, S5[3] = {0.f, 0.f, 0.f};
    for (int ky = 0; ky < 7; ++ky)
        for (int kx = 0; kx < 7; ++kx) {
            float dy = (float)(ky - 3), dx = (float)(kx - 3);
            float rr = sqrtf(dy * dy + dx * dx);
            for (int r = 0; r < 3; ++r) { float d = rr - (float)(r + 1); SA[r] += expf(-2.f * d * d); }
        }
    for (int ky = 0; ky < 5; ++ky)
        for (int kx = 0; kx < 5; ++kx) {
            float dy = (float)(ky - 2), dx = (float)(kx - 2);
            float rr = sqrtf(dy * dy + dx * dx);
            for (int r = 0; r < 3; ++r) { float d = rr - (float)r; S5[r] += expf(-2.f * d * d); }
        }

    setup_kernel<<<dim3(3568 + 544), dim3(256), 0, stream>>>(
        w0, wc, wsn, wa, x, KA, KB, Xt,
        SA[0], SA[1], SA[2], S5[0], S5[1], S5[2]);

    fused_kernel<<<dim3(64, 8, 4), dim3(256), 0, stream>>>(Xt, KA, KB, bias, out);
}

// Round 7
// 234.002 us; speedup vs baseline: 1.0175x; 1.0175x over previous
//
#include <hip/hip_runtime.h>
#include <math.h>

// SteeredConvTranspose2d on MI355X — round 7: N=8 wave tile (2 output rows).
// setup (prep weights*basis -> bf16  +  transpose/pad/pre-swizzle x -> Xt) ;
// fused conv: wave = 7 chunks x 16 oc x 128 px; weights double-buffered by
// compile-time phase; X staged via global_load_lds (pre-swizzled, per-lane src).
//
// ws layout (bytes):
//   [0       .. 802816)    KA bf16 [e 49][uv 2][oc 64][i 64]
//   [802816  .. 1826816)   KB bf16 [e 25][oc 320][i 64]
//   [2097152 .. +4734976)  Xt bf16 [8][68][68][64]  zero-padded halo, granule-swizzled

namespace {

typedef float f4 __attribute__((ext_vector_type(4)));
typedef short s8 __attribute__((ext_vector_type(8)));

constexpr int NKA = 401408;   // 49*2*64*64
constexpr int NKB = 512000;   // 25*320*64

__device__ __forceinline__ unsigned short f2bf(float f) {
    unsigned int u = __float_as_uint(f);
    u += 0x7fffu + ((u >> 16) & 1u);
    return (unsigned short)(u >> 16);
}

template <int PY, int PX>
constexpr unsigned bmaskA() {
    constexpr int NXA = 4 - PX, NYA = 4 - PY, NXB = 2 + PX, NYB = 2 + PY;
    unsigned m = 0;
    for (int t = 0; t < NYA * NXA; ++t) {
        int tyi = t / NXA, txi = t % NXA;
        int ty = tyi - (1 - PY), tx = txi - (1 - PX);
        if (ty >= 0 && ty < NYB && tx >= 0 && tx < NXB) m |= 1u << t;
    }
    return m;
}

// ---------------- setup: prep (weights*basis) + transpose/pad/swizzle x ----------------
__device__ void prep_body(
    const float* __restrict__ w0, const float* __restrict__ wc,
    const float* __restrict__ wsn, const float* __restrict__ wa,
    unsigned short* __restrict__ KA, unsigned short* __restrict__ KB,
    const float* SA, const float* S5)
{
    const int idx = blockIdx.x * 256 + threadIdx.x;
    if (idx < NKA) {
        int i = idx & 63;
        int e = idx >> 6;
        int oc = e & 63; e >>= 6;
        int uv = e & 1;  e >>= 1;     // e in [0,49) cumulative tap over parities {16,12,12,9}
        int par = (e < 16) ? 0 : (e < 28) ? 1 : (e < 40) ? 2 : 3;
        int t = e - ((par == 0) ? 0 : (par == 1) ? 16 : (par == 2) ? 28 : 40);
        int py = par >> 1, px = par & 1;
        int nx = 4 - px;
        int tyi = t / nx, txi = t % nx;
        float dy = (float)(2 * tyi + py - 3), dx = (float)(2 * txi + px - 3);
        float rr = sqrtf(dy * dy + dx * dx);
        float phi = atan2f(dy, dx);
        const float* wr = wa + (oc * 64 + i) * 3;
        float v = 0.f;
#pragma unroll
        for (int r = 0; r < 3; ++r) { float d = rr - (float)(r + 1); v += wr[r] * (expf(-2.f * d * d) / SA[r]); }
        float tr = uv ? sinf(phi) : cosf(phi);
        KA[idx] = f2bf(v * tr);
    } else if (idx < NKA + NKB) {
        int j = idx - NKA;
        int i = j & 63;
        int rest = j >> 6;
        int oc = rest % 320;
        int e = rest / 320;           // [0,25) cumulative tap over parities {4,6,6,9}
        int par = (e < 4) ? 0 : (e < 10) ? 1 : (e < 16) ? 2 : 3;
        int t = e - ((par == 0) ? 0 : (par == 1) ? 4 : (par == 2) ? 10 : 16);
        int py = par >> 1, px = par & 1;
        int nx = 2 + px;
        int tyi = t / nx, txi = t % nx;
        float dy = (float)(2 * tyi - 1 - py), dx = (float)(2 * txi - 1 - px);
        float rr = sqrtf(dy * dy + dx * dx);
        float phi = atan2f(dy, dx);
        int g = oc >> 6, o = oc & 63;
        float v = 0.f;
        if (g == 0) {
            const float* wr = w0 + (o * 64 + i) * 3;
#pragma unroll
            for (int r = 0; r < 3; ++r) { float d = rr - (float)r; v += wr[r] * (expf(-2.f * d * d) / S5[r]); }
        } else {
            int k = (g - 1) >> 1, sn = (g - 1) & 1;
            const float* wsel = ((sn == 0) ? wc : wsn) + ((k * 64 + o) * 64 + i) * 2;
            float s = 0.f;
#pragma unroll
            for (int r = 0; r < 2; ++r) { float d = rr - (float)(r + 1); s += wsel[r] * (expf(-2.f * d * d) / S5[r + 1]); }
            float ang = (float)(k + 1) * phi;
            v = s * ((sn == 0) ? cosf(ang) : sinf(ang));
        }
        KB[j] = f2bf(v);
    }
}

// x fp32 NCHW -> Xt bf16 [b][iyp 68][ixp 68][granule-swizzled ch 64]
// granule slot = (ch>>3) ^ (ixp & 7)  (involution; fused staging is then linear)
__device__ void transpose_body(
    const float* __restrict__ x, unsigned short* __restrict__ Xt, float* LFraw)
{
    float (*LF)[65] = (float (*)[65])LFraw;
    const int t = threadIdx.x;
    const int j = blockIdx.x - 3568;
    const int iyp = j % 68, b = j / 68;
    const int iy = iyp - 2;
    unsigned int* Xtu = (unsigned int*)(Xt + (size_t)(b * 68 + iyp) * 68 * 64);
    if (iy < 0 || iy >= 64) {
        for (int k = t; k < 68 * 32; k += 256) Xtu[k] = 0u;
        return;
    }
    const float* xb = x + (size_t)b * 262144 + iy * 64;
#pragma unroll
    for (int it = 0; it < 16; ++it) {
        int ch = it * 4 + (t >> 6);
        LF[ch][t & 63] = xb[(size_t)ch * 4096 + (t & 63)];
    }
    __syncthreads();
    if (t < 128) {   // zero border cols ixp in {0,1,66,67}
        int colidx = t >> 5;
        int ixp = (colidx < 2) ? colidx : 64 + colidx;
        Xtu[ixp * 32 + (t & 31)] = 0u;
    }
    const int lane = t & 63, w = t >> 6;
#pragma unroll
    for (int k = 0; k < 8; ++k) {
        int it = w * 8 + k;                 // 0..31
        int ix = 2 * it + (lane >> 5);      // 0..63
        int ch = 2 * (lane & 31);
        unsigned int pack = (unsigned int)f2bf(LF[ch][ix]) | ((unsigned int)f2bf(LF[ch + 1][ix]) << 16);
        const int ixp = ix + 2;
        const int gslot = ((lane & 31) >> 2) ^ (ixp & 7);
        Xtu[ixp * 32 + gslot * 4 + ((lane & 31) & 3)] = pack;
    }
}

__global__ __launch_bounds__(256) void setup_kernel(
    const float* __restrict__ w0, const float* __restrict__ wc,
    const float* __restrict__ wsn, const float* __restrict__ wa,
    const float* __restrict__ x,
    unsigned short* __restrict__ KA, unsigned short* __restrict__ KB,
    unsigned short* __restrict__ Xt,
    float sa0, float sa1, float sa2, float s50, float s51, float s52)
{
    __shared__ float LFraw[64 * 65];
    const float SA[3] = {sa0, sa1, sa2};
    const float S5[3] = {s50, s51, s52};
    if (blockIdx.x < 3568) prep_body(w0, wc, wsn, wa, KA, KB, SA, S5);
    else                   transpose_body(x, Xt, LFraw);
}

// ---------------- fused conv: N=8 (2-row) MFMA loop ----------------
template <int PY, int PX>
__device__ __forceinline__ void mfma_loop(
    const unsigned short* __restrict__ Xs,
    const unsigned short* __restrict__ KA, const unsigned short* __restrict__ KB,
    const float* __restrict__ bias, float* __restrict__ out,
    int b, int oy0, int obase, int lr, int hi)
{
    constexpr int NXA = 4 - PX, NYA = 4 - PY, NTA = NYA * NXA;
    constexpr int PAR = 2 * PY + PX;
    constexpr int TBA = (PAR == 0) ? 0 : (PAR == 1) ? 16 : (PAR == 2) ? 28 : 40;
    constexpr int TBB = (PAR == 0) ? 0 : (PAR == 1) ? 4  : (PAR == 2) ? 10 : 16;
    constexpr unsigned BM = bmaskA<PY, PX>();

    const unsigned short* ka = KA + TBA * 8192  + (obase + lr) * 64 + hi * 8;
    const unsigned short* kb = KB + TBB * 20480 + (obase + lr) * 64 + hi * 8;

    f4 accA[2][8];
    f4 accB[5][8];
#pragma unroll
    for (int uv = 0; uv < 2; ++uv)
#pragma unroll
        for (int ni = 0; ni < 8; ++ni) accA[uv][ni] = f4{0.f, 0.f, 0.f, 0.f};
#pragma unroll
    for (int g = 0; g < 5; ++g)
#pragma unroll
        for (int ni = 0; ni < 8; ++ni) accB[g][ni] = f4{0.f, 0.f, 0.f, 0.f};

    // weight regs, double-buffered by compile-time phase
    s8 aw[2][2], gw[2][5];

    // prologue: step 0 weights into phase 0
    {
#pragma unroll
        for (int uv = 0; uv < 2; ++uv)
            aw[0][uv] = *(const s8*)(ka + 0 * 8192 + uv * 4096 + 0 * 32);
        if (BM & 1u) {
#pragma unroll
            for (int g = 0; g < 5; ++g)
                gw[0][g] = *(const s8*)(kb + 0 * 20480 + g * 4096 + 0 * 32);
        }
    }

#pragma unroll
    for (int s = 0; s < 2 * NTA; ++s) {
        const int t = s >> 1, ks = s & 1, ph = s & 1;
        const int tyi = t / NXA, txi = t % NXA;
        const bool bv = (BM >> t) & 1u;
        // issue next step's weights into the other phase
        if (s + 1 < 2 * NTA) {
            const int tn = (s + 1) >> 1, ksn = (s + 1) & 1;
            const int tBn = __builtin_popcount(BM & ((1u << tn) - 1u));
#pragma unroll
            for (int uv = 0; uv < 2; ++uv)
                aw[ph ^ 1][uv] = *(const s8*)(ka + tn * 8192 + uv * 4096 + ksn * 32);
            if ((BM >> tn) & 1u) {
#pragma unroll
                for (int g = 0; g < 5; ++g)
                    gw[ph ^ 1][g] = *(const s8*)(kb + tBn * 20480 + g * 4096 + ksn * 32);
            }
        }
        // X fragments: 2 rows x 4 col-frags
        s8 xf[8];
#pragma unroll
        for (int ni = 0; ni < 8; ++ni) {
            const int row = tyi + (ni >> 2);
            const int rx = (ni & 3) * 16 + lr + txi + PX;
            const int gz = (ks * 4 + hi) ^ (rx & 7);
            xf[ni] = *(const s8*)(Xs + ((row * 68 + rx) * 8 + gz) * 8);
        }
        // MFMAs
#pragma unroll
        for (int uv = 0; uv < 2; ++uv)
#pragma unroll
            for (int ni = 0; ni < 8; ++ni)
                accA[uv][ni] = __builtin_amdgcn_mfma_f32_16x16x32_bf16(aw[ph][uv], xf[ni], accA[uv][ni], 0, 0, 0);
        if (bv) {
#pragma unroll
            for (int g = 0; g < 5; ++g)
#pragma unroll
                for (int ni = 0; ni < 8; ++ni)
                    accB[g][ni] = __builtin_amdgcn_mfma_f32_16x16x32_bf16(gw[ph][g], xf[ni], accB[g][ni], 0, 0, 0);
        }
    }

    // epilogue: gating + bias
#pragma unroll
    for (int ni = 0; ni < 8; ++ni) {
        const int yy = 2 * (oy0 + (ni >> 2)) + PY;
        const int px = (ni & 3) * 16 + lr;
        const int xx = 2 * px + PX;
#pragma unroll
        for (int r2 = 0; r2 < 4; ++r2) {
            const int o = obase + hi * 4 + r2;
            const float u = accA[0][ni][r2], v = accA[1][ni][r2];
            const float rho_raw = sqrtf(u * u + v * v + 1e-8f);
            const float un = u / rho_raw, vn = v / rho_raw;
            const float rho = tanhf(rho_raw);
            const float c2 = (un - vn) * (un + vn);
            const float sp = 2.f * un * vn;
            out[((b * 64 + o) * 128 + yy) * 128 + xx] =
                accB[0][ni][r2]
                + rho * (un * accB[1][ni][r2] + vn * accB[2][ni][r2]
                       + c2 * accB[3][ni][r2] + sp * accB[4][ni][r2])
                + bias[o];
        }
    }
}

template <int PY>
__device__ __forceinline__ void fused_body(
    const unsigned short* __restrict__ Xt,
    const unsigned short* __restrict__ KA, const unsigned short* __restrict__ KB,
    const float* __restrict__ bias, float* __restrict__ out,
    int oh, unsigned short* Xs)
{
    constexpr int NYA = 4 - PY;
    const int tid = threadIdx.x;
    const int oy0 = 2 * blockIdx.x, b = blockIdx.y;

    // ---- stage NYA+1 contiguous rows of (pre-swizzled) Xt into LDS ----
    // LDS dest: wave-uniform base (HW scatters lane*16B). Global src: PER-LANE address.
    {
        const int iy0p = oy0 + PY;                        // first padded row
        const int lane = tid & 63;
        const unsigned short* src = Xt + ((size_t)b * 68 + iy0p) * 68 * 64;
        constexpr int NCH = ((NYA + 1) * 68 * 8 + 63) / 64;  // 1KiB chunks (ceil)
        const int wv = tid >> 6;
        for (int c = wv; c < NCH; c += 4)
            __builtin_amdgcn_global_load_lds((const unsigned int*)(src + c * 512 + lane * 8),
                                             (unsigned int*)(Xs + c * 512), 16, 0, 0);
    }
    __syncthreads();

    const int lane = tid & 63, lr = lane & 15, hi = lane >> 4;
    const int w = tid >> 6;
    const int p = w & 1, mq = w >> 1;
    const int obase = oh * 32 + mq * 16;

    if (p == 0)
        mfma_loop<PY, 0>(Xs, KA, KB, bias, out, b, oy0, obase, lr, hi);
    else
        mfma_loop<PY, 1>(Xs, KA, KB, bias, out, b, oy0, obase, lr, hi);
}

__global__ __launch_bounds__(256, 1) void fused_kernel(
    const unsigned short* __restrict__ Xt,
    const unsigned short* __restrict__ KA, const unsigned short* __restrict__ KB,
    const float* __restrict__ bias, float* __restrict__ out)
{
    __shared__ __align__(16) unsigned short Xs[22016];   // 5*68*64 rounded up to 1KiB chunks
    const int z = blockIdx.z;
    const int oh = z >> 1;
    if (z & 1) fused_body<1>(Xt, KA, KB, bias, out, oh, Xs);
    else       fused_body<0>(Xt, KA, KB, bias, out, oh, Xs);
}

} // namespace

extern "C" void kernel_launch(void* const* d_in, const int* in_sizes, int n_in,
                              void* d_out, int out_size, void* d_ws, size_t ws_size,
                              hipStream_t stream)
{
    const float* x    = (const float*)d_in[0];
    const float* w0   = (const float*)d_in[1];
    const float* wc   = (const float*)d_in[2];
    const float* wsn  = (const float*)d_in[3];
    const float* wa   = (const float*)d_in[4];
    const float* bias = (const float*)d_in[5];
    float* out = (float*)d_out;

    char* wsb = (char*)d_ws;
    unsigned short* KA = (unsigned short*)(wsb);
    unsigned short* KB = (unsigned short*)(wsb + 802816);
    unsigned short* Xt = (unsigned short*)(wsb + 2097152);

    // host-side radial normalization constants (pure CPU math, capture-safe)
    float SA[3] = {0.f, 0.f, 0.f}, S5[3] = {0.f, 0.f, 0.f};
    for (int ky = 0; ky < 7; ++ky)
        for (int kx = 0; kx < 7; ++kx) {
            float dy = (float)(ky - 3), dx = (float)(kx - 3);
            float rr = sqrtf(dy * dy + dx * dx);
            for (int r = 0; r < 3; ++r) { float d = rr - (float)(r + 1); SA[r] += expf(-2.f * d * d); }
        }
    for (int ky = 0; ky < 5; ++ky)
        for (int kx = 0; kx < 5; ++kx) {
            float dy = (float)(ky - 2), dx = (float)(kx - 2);
            float rr = sqrtf(dy * dy + dx * dx);
            for (int r = 0; r < 3; ++r) { float d = rr - (float)r; S5[r] += expf(-2.f * d * d); }
        }

    setup_kernel<<<dim3(3568 + 544), dim3(256), 0, stream>>>(
        w0, wc, wsn, wa, x, KA, KB, Xt,
        SA[0], SA[1], SA[2], S5[0], S5[1], S5[2]);

    fused_kernel<<<dim3(32, 8, 4), dim3(256), 0, stream>>>(Xt, KA, KB, bias, out);
}

// Round 8
// 201.137 us; speedup vs baseline: 1.1837x; 1.1634x over previous
//
#include <hip/hip_runtime.h>
#include <math.h>

// SteeredConvTranspose2d on MI355X — round 8: persistent-operand fused kernel.
// setup: prep (weights*basis -> bf16; KB pre-swizzled for LDS) + transpose/pad x.
// fused: 1 WG/CU. u,v-weights in VGPRs (per ks-half), 5-group weights in LDS
// (staged once), X rows in LDS (per 4-oy group). Inner loop = LDS + MFMA only.
//
// ws layout (bytes):
//   [0       .. 802816)    KA bf16 [e 49][uv 2][oc 64][i 64]                (reg loads)
//   [802816  .. 1826816)   KB bf16 [par][mq 4][t NTB][g 5][oc 16][i 64 swz] (LDS loads)
//   [2097152 .. +4734976)  Xt bf16 [8][68][68][64] zero-padded halo, granule-swizzled

namespace {

typedef float f4 __attribute__((ext_vector_type(4)));
typedef short s8 __attribute__((ext_vector_type(8)));

constexpr int NKA = 401408;   // 49*2*64*64
constexpr int NKB = 512000;   // sum_par 4mq*NTB*5*16*64
constexpr int OFFBC[4] = {0, 81920, 204800, 327680};   // KB element offset per par

__device__ __forceinline__ unsigned short f2bf(float f) {
    unsigned int u = __float_as_uint(f);
    u += 0x7fffu + ((u >> 16) & 1u);
    return (unsigned short)(u >> 16);
}

template <int PY, int PX>
constexpr unsigned bmaskA() {
    constexpr int NXA = 4 - PX, NYA = 4 - PY, NXB = 2 + PX, NYB = 2 + PY;
    unsigned m = 0;
    for (int t = 0; t < NYA * NXA; ++t) {
        int tyi = t / NXA, txi = t % NXA;
        int ty = tyi - (1 - PY), tx = txi - (1 - PX);
        if (ty >= 0 && ty < NYB && tx >= 0 && tx < NXB) m |= 1u << t;
    }
    return m;
}

// ---------------- setup: prep (weights*basis) + transpose/pad/swizzle x ----------------
__device__ void prep_body(
    const float* __restrict__ w0, const float* __restrict__ wc,
    const float* __restrict__ wsn, const float* __restrict__ wa,
    unsigned short* __restrict__ KA, unsigned short* __restrict__ KB,
    const float* SA, const float* S5)
{
    const int idx = blockIdx.x * 256 + threadIdx.x;
    if (idx < NKA) {
        // KA unchanged: [e 49][uv 2][oc 64][i 64]
        int i = idx & 63;
        int e = idx >> 6;
        int oc = e & 63; e >>= 6;
        int uv = e & 1;  e >>= 1;
        int par = (e < 16) ? 0 : (e < 28) ? 1 : (e < 40) ? 2 : 3;
        int t = e - ((par == 0) ? 0 : (par == 1) ? 16 : (par == 2) ? 28 : 40);
        int py = par >> 1, px = par & 1;
        int nx = 4 - px;
        int tyi = t / nx, txi = t % nx;
        float dy = (float)(2 * tyi + py - 3), dx = (float)(2 * txi + px - 3);
        float rr = sqrtf(dy * dy + dx * dx);
        float phi = atan2f(dy, dx);
        const float* wr = wa + (oc * 64 + i) * 3;
        float v = 0.f;
#pragma unroll
        for (int r = 0; r < 3; ++r) { float d = rr - (float)(r + 1); v += wr[r] * (expf(-2.f * d * d) / SA[r]); }
        float tr = uv ? sinf(phi) : cosf(phi);
        KA[idx] = f2bf(v * tr);
    } else if (idx < NKA + NKB) {
        // KB new layout: [par][mq][t][g][oc16][i64], ch-granule swizzled by (oc16&7)
        int j = idx - NKA;
        int par = (j < OFFBC[1]) ? 0 : (j < OFFBC[2]) ? 1 : (j < OFFBC[3]) ? 2 : 3;
        int py = par >> 1, px = par & 1;
        int nx = 2 + px;
        int ntb = (2 + py) * nx;
        int j2 = j - OFFBC[par];
        int per = ntb * 5120;
        int mq = j2 / per;
        int r1 = j2 - mq * per;
        int t = r1 / 5120;
        int r2 = r1 - t * 5120;
        int g = r2 >> 10;
        int oc16 = (r2 >> 6) & 15;
        int i_s = r2 & 63;
        int i = (((i_s >> 3) ^ (oc16 & 7)) << 3) | (i_s & 7);   // involution
        int o = mq * 16 + oc16;
        int tyi = t / nx, txi = t % nx;
        float dy = (float)(2 * tyi - 1 - py), dx = (float)(2 * txi - 1 - px);
        float rr = sqrtf(dy * dy + dx * dx);
        float phi = atan2f(dy, dx);
        float v = 0.f;
        if (g == 0) {
            const float* wr = w0 + (o * 64 + i) * 3;
#pragma unroll
            for (int r = 0; r < 3; ++r) { float d = rr - (float)r; v += wr[r] * (expf(-2.f * d * d) / S5[r]); }
        } else {
            int k = (g - 1) >> 1, sn = (g - 1) & 1;
            const float* wsel = ((sn == 0) ? wc : wsn) + ((k * 64 + o) * 64 + i) * 2;
            float s = 0.f;
#pragma unroll
            for (int r = 0; r < 2; ++r) { float d = rr - (float)(r + 1); s += wsel[r] * (expf(-2.f * d * d) / S5[r + 1]); }
            float ang = (float)(k + 1) * phi;
            v = s * ((sn == 0) ? cosf(ang) : sinf(ang));
        }
        KB[j] = f2bf(v);
    }
}

// x fp32 NCHW -> Xt bf16 [b][iyp 68][ixp 68][granule-swizzled ch 64]
__device__ void transpose_body(
    const float* __restrict__ x, unsigned short* __restrict__ Xt, float* LFraw)
{
    float (*LF)[65] = (float (*)[65])LFraw;
    const int t = threadIdx.x;
    const int j = blockIdx.x - 3568;
    const int iyp = j % 68, b = j / 68;
    const int iy = iyp - 2;
    unsigned int* Xtu = (unsigned int*)(Xt + (size_t)(b * 68 + iyp) * 68 * 64);
    if (iy < 0 || iy >= 64) {
        for (int k = t; k < 68 * 32; k += 256) Xtu[k] = 0u;
        return;
    }
    const float* xb = x + (size_t)b * 262144 + iy * 64;
#pragma unroll
    for (int it = 0; it < 16; ++it) {
        int ch = it * 4 + (t >> 6);
        LF[ch][t & 63] = xb[(size_t)ch * 4096 + (t & 63)];
    }
    __syncthreads();
    if (t < 128) {   // zero border cols ixp in {0,1,66,67}
        int colidx = t >> 5;
        int ixp = (colidx < 2) ? colidx : 64 + colidx;
        Xtu[ixp * 32 + (t & 31)] = 0u;
    }
    const int lane = t & 63, w = t >> 6;
#pragma unroll
    for (int k = 0; k < 8; ++k) {
        int it = w * 8 + k;
        int ix = 2 * it + (lane >> 5);
        int ch = 2 * (lane & 31);
        unsigned int pack = (unsigned int)f2bf(LF[ch][ix]) | ((unsigned int)f2bf(LF[ch + 1][ix]) << 16);
        const int ixp = ix + 2;
        const int gslot = ((lane & 31) >> 2) ^ (ixp & 7);
        Xtu[ixp * 32 + gslot * 4 + ((lane & 31) & 3)] = pack;
    }
}

__global__ __launch_bounds__(256) void setup_kernel(
    const float* __restrict__ w0, const float* __restrict__ wc,
    const float* __restrict__ wsn, const float* __restrict__ wa,
    const float* __restrict__ x,
    unsigned short* __restrict__ KA, unsigned short* __restrict__ KB,
    unsigned short* __restrict__ Xt,
    float sa0, float sa1, float sa2, float s50, float s51, float s52)
{
    __shared__ float LFraw[64 * 65];
    const float SA[3] = {sa0, sa1, sa2};
    const float S5[3] = {s50, s51, s52};
    if (blockIdx.x < 3568) prep_body(w0, wc, wsn, wa, KA, KB, SA, S5);
    else                   transpose_body(x, Xt, LFraw);
}

// ---------------- fused conv: persistent operands, 1 WG/CU ----------------
template <int PY, int PX>
__device__ __forceinline__ void conv_body(
    const unsigned short* __restrict__ Xt,
    const unsigned short* __restrict__ KA, const unsigned short* __restrict__ KB,
    const float* __restrict__ bias, float* __restrict__ out,
    int mq, int tg, char* lds)
{
    constexpr int NXA = 4 - PX, NYA = 4 - PY, NTA = NYA * NXA;
    constexpr int NXB = 2 + PX, NYB = 2 + PY, NTB = NYB * NXB;
    constexpr int PAR = 2 * PY + PX;
    constexpr int TBA = (PAR == 0) ? 0 : (PAR == 1) ? 16 : (PAR == 2) ? 28 : 40;
    constexpr unsigned BM = bmaskA<PY, PX>();
    constexpr int XROWS = NYA + 3;                       // X rows per 4-oy group
    constexpr int XCH = (XROWS * 8704 + 1023) / 1024;    // 1KiB staging chunks
    constexpr int WBCH = NTB * 10;                       // WB bytes/1024

    unsigned short* WB = (unsigned short*)lds;
    unsigned short* Xs = (unsigned short*)(lds + WBCH * 1024);

    const int tid = threadIdx.x;
    const int lane = tid & 63, lr = lane & 15, hi = lane >> 4;
    const int wv = tid >> 6;          // wave id = oy offset within group
    const int obase = mq * 16;

    // ---- stage WB once (linear copy; swizzle pre-applied by prep) ----
    {
        const unsigned short* kbsrc = KB + OFFBC[PAR] + mq * (NTB * 5120);
        for (int c = wv; c < WBCH; c += 4)
            __builtin_amdgcn_global_load_lds((const unsigned int*)(kbsrc + c * 512 + lane * 8),
                                             (unsigned int*)(WB + c * 512), 16, 0, 0);
    }

    auto loadX = [&](s8 (&d)[4], int tyi, int txi, int ks) {
        const int lrow = wv + tyi;
#pragma unroll
        for (int ni = 0; ni < 4; ++ni) {
            const int rx = ni * 16 + lr + txi + PX;
            const int gz = (ks * 4 + hi) ^ (rx & 7);
            d[ni] = *(const s8*)(Xs + ((lrow * 68 + rx) * 8 + gz) * 8);
        }
    };

    for (int gi = 0; gi < 8; ++gi) {
        const int G = tg * 8 + gi;
        const int b = G >> 4;
        const int oy0 = (G & 15) * 4;

        // ---- stage X rows [oy0+PY, +XROWS) of Xt (pre-swizzled, linear) ----
        {
            const unsigned short* xsrc = Xt + (size_t)(b * 68 + oy0 + PY) * 4352;
            for (int c = wv; c < XCH; c += 4)
                __builtin_amdgcn_global_load_lds((const unsigned int*)(xsrc + c * 512 + lane * 8),
                                                 (unsigned int*)(Xs + c * 512), 16, 0, 0);
        }
        __syncthreads();

        f4 accA[2][4];
        f4 accB[5][4];
#pragma unroll
        for (int uv = 0; uv < 2; ++uv)
#pragma unroll
            for (int ni = 0; ni < 4; ++ni) accA[uv][ni] = f4{0.f, 0.f, 0.f, 0.f};
#pragma unroll
        for (int g = 0; g < 5; ++g)
#pragma unroll
            for (int ni = 0; ni < 4; ++ni) accB[g][ni] = f4{0.f, 0.f, 0.f, 0.f};

#pragma unroll
        for (int ksp = 0; ksp < 2; ++ksp) {
            // u,v weights for this ks-half -> registers (2*NTA frags)
            s8 aA[NTA][2];
#pragma unroll
            for (int t = 0; t < NTA; ++t)
#pragma unroll
                for (int uv = 0; uv < 2; ++uv)
                    aA[t][uv] = *(const s8*)(KA + (((TBA + t) * 2 + uv) * 64 + obase + lr) * 64 + ksp * 32 + hi * 8);

            s8 xf[2][4];
            loadX(xf[0], 0, 0, ksp);
#pragma unroll
            for (int t = 0; t < NTA; ++t) {
                const int ph = t & 1;
                const bool bv = (BM >> t) & 1u;
                const int tB = __builtin_popcount(BM & ((1u << t) - 1u));
                if (t + 1 < NTA) loadX(xf[ph ^ 1], (t + 1) / NXA, (t + 1) % NXA, ksp);
                s8 gw[5];
                if (bv) {
#pragma unroll
                    for (int g = 0; g < 5; ++g)
                        gw[g] = *(const s8*)(WB + ((tB * 5 + g) * 16 + lr) * 64 + ((ksp * 4 + hi) ^ (lr & 7)) * 8);
                }
#pragma unroll
                for (int uv = 0; uv < 2; ++uv)
#pragma unroll
                    for (int ni = 0; ni < 4; ++ni)
                        accA[uv][ni] = __builtin_amdgcn_mfma_f32_16x16x32_bf16(aA[t][uv], xf[ph][ni], accA[uv][ni], 0, 0, 0);
                if (bv) {
#pragma unroll
                    for (int g = 0; g < 5; ++g)
#pragma unroll
                        for (int ni = 0; ni < 4; ++ni)
                            accB[g][ni] = __builtin_amdgcn_mfma_f32_16x16x32_bf16(gw[g], xf[ph][ni], accB[g][ni], 0, 0, 0);
                }
            }
        }

        // ---- epilogue: gating + bias; wave wv owns oy = oy0+wv ----
        const int yy = 2 * (oy0 + wv) + PY;
#pragma unroll
        for (int ni = 0; ni < 4; ++ni) {
            const int px = ni * 16 + lr;
            const int xx = 2 * px + PX;
#pragma unroll
            for (int r2 = 0; r2 < 4; ++r2) {
                const int o = obase + hi * 4 + r2;
                const float u = accA[0][ni][r2], v = accA[1][ni][r2];
                const float rho_raw = sqrtf(u * u + v * v + 1e-8f);
                const float un = u / rho_raw, vn = v / rho_raw;
                const float rho = tanhf(rho_raw);
                const float c2 = (un - vn) * (un + vn);
                const float sp = 2.f * un * vn;
                out[((b * 64 + o) * 128 + yy) * 128 + xx] =
                    accB[0][ni][r2]
                    + rho * (un * accB[1][ni][r2] + vn * accB[2][ni][r2]
                           + c2 * accB[3][ni][r2] + sp * accB[4][ni][r2])
                    + bias[o];
            }
        }
        __syncthreads();   // all waves done reading Xs before next group's stage
    }
}

__global__ __launch_bounds__(256, 1) void fused_kernel(
    const unsigned short* __restrict__ Xt,
    const unsigned short* __restrict__ KA, const unsigned short* __restrict__ KB,
    const float* __restrict__ bias, float* __restrict__ out)
{
    __shared__ __align__(16) char lds[144384];   // max over par: WB + X chunks
    const int tg = blockIdx.x;
    const int y = blockIdx.y;
    const int mq = y & 3;
    switch (y >> 2) {
        case 0:  conv_body<0, 0>(Xt, KA, KB, bias, out, mq, tg, lds); break;
        case 1:  conv_body<0, 1>(Xt, KA, KB, bias, out, mq, tg, lds); break;
        case 2:  conv_body<1, 0>(Xt, KA, KB, bias, out, mq, tg, lds); break;
        default: conv_body<1, 1>(Xt, KA, KB, bias, out, mq, tg, lds); break;
    }
}

} // namespace

extern "C" void kernel_launch(void* const* d_in, const int* in_sizes, int n_in,
                              void* d_out, int out_size, void* d_ws, size_t ws_size,
                              hipStream_t stream)
{
    const float* x    = (const float*)d_in[0];
    const float* w0   = (const float*)d_in[1];
    const float* wc   = (const float*)d_in[2];
    const float* wsn  = (const float*)d_in[3];
    const float* wa   = (const float*)d_in[4];
    const float* bias = (const float*)d_in[5];
    float* out = (float*)d_out;

    char* wsb = (char*)d_ws;
    unsigned short* KA = (unsigned short*)(wsb);
    unsigned short* KB = (unsigned short*)(wsb + 802816);
    unsigned short* Xt = (unsigned short*)(wsb + 2097152);

    // host-side radial normalization constants (pure CPU math, capture-safe)
    float SA[3] = {0.f, 0.f, 0.f}, S5[3] = {0.f, 0.f, 0.f};
    for (int ky = 0; ky < 7; ++ky)
        for (int kx = 0; kx < 7; ++kx) {
            float dy = (float)(ky - 3), dx = (float)(kx - 3);
            float rr = sqrtf(dy * dy + dx * dx);
            for (int r = 0; r < 3; ++r) { float d = rr - (float)(r + 1); SA[r] += expf(-2.f * d * d); }
        }
    for (int ky = 0; ky < 5; ++ky)
        for (int kx = 0; kx < 5; ++kx) {
            float dy = (float)(ky - 2), dx = (float)(kx - 2);
            float rr = sqrtf(dy * dy + dx * dx);
            for (int r = 0; r < 3; ++r) { float d = rr - (float)r; S5[r] += expf(-2.f * d * d); }
        }

    setup_kernel<<<dim3(3568 + 544), dim3(256), 0, stream>>>(
        w0, wc, wsn, wa, x, KA, KB, Xt,
        SA[0], SA[1], SA[2], S5[0], S5[1], S5[2]);

    fused_kernel<<<dim3(16, 16), dim3(256), 0, stream>>>(Xt, KA, KB, bias, out);
}